// Round 11
// baseline (161.102 us; speedup 1.0000x reference)
//
#include <hip/hip_runtime.h>
#include <math.h>

// EKF over 2048 trajectories, T=512 serial steps. ONE LANE PER TRAJECTORY
// (32 waves); all three decomposed 2-state filters (x, y, theta) in-lane —
// three independent dependency chains interleave to fill stall slots.
//
// R11 vs R10: R10 regressed because __launch_bounds__(64) (missing ",1")
// let the occupancy heuristic cap VGPRs at ~64 -> A/B z-tiles spilled to
// scratch -> per-step private-memory loads (VGPR=52, VALUBusy at 73% of the
// 32-CU ceiling = issue-bound on spill code). Fixes:
//   - __launch_bounds__(64, 1): full VGPR budget, tiles stay in registers
//   - sched_barrier(0) + memory clobber after each prefetch block: loads
//     can't sink to use; B-tile loads stay in flight across A-steps
//   - loss algebra reuses ry (y^2*rs = y*ry): -2 insts/step.

#define CEXP 288.53900817779268f   // 200 * log2(e)

__device__ __forceinline__ float frcp(float x) { return __builtin_amdgcn_rcpf(x); }

// Pin instruction regions: nothing crosses (scheduler), memory ops ordered
// (compiler IR).
__device__ __forceinline__ void pin() {
    __builtin_amdgcn_sched_barrier(0);
    asm volatile("" ::: "memory");
}

// One EKF step for all three in-lane filters. z components are compile-time
// register selects; LT is an lvalue (float4 component) receiving the loss.
// tanh chain: w = 1/(exp2(c*v)+1); 1-tanh^2 = 4w(1-w); -cf*tanh = 2cf*w-cf.
// exp2 over/underflow round-trips correctly (inf->w=0, 0->w=1).
#define STEP(z0, z1, z2, LT) do {                                          \
    const float eX = exp2f(CEXP * DX);                                     \
    const float eY = exp2f(CEXP * DY);                                     \
    const float wX = frcp(eX + 1.0f);                                      \
    const float wY = frcp(eY + 1.0f);                                      \
    const float wwX = fmaf(wX, -wX, wX);                                   \
    const float wwY = fmaf(wY, -wY, wY);                                   \
    const float aX = fmaf(m4cb, wwX, ca);                                  \
    const float aY = fmaf(m4cb, wwY, ca);                                  \
    const float uX = fmaf(DTc, px22, px02);                                \
    const float uY = fmaf(DTc, py33, py13);                                \
    const float uT = fmaf(DTc, pt55, pt45);                                \
    const float p0X = fmaf(DTc, px02 + uX, px00) + qx00;                   \
    const float p0Y = fmaf(DTc, py13 + uY, py11) + qy11;                   \
    const float p0T = fmaf(DTc, pt45 + uT, pt44) + qt44;                   \
    const float p2X = fmaf(aX, uX, qxc);                                   \
    const float p2Y = fmaf(aY, uY, qyc);                                   \
    const float p2T = uT + qtc;                                            \
    const float pvX = fmaf(aX * px22, aX, qx22);                           \
    const float pvY = fmaf(aY * py33, aY, qy33);                           \
    const float pvT = pt55 + qt55;                                         \
    const float spX = fmaf(DTc, DX, X);                                    \
    const float spY = fmaf(DTc, DY, Y);                                    \
    const float spT = fmaf(DTc, DTH, TH);                                  \
    const float svX = fmaf(cf2, wX, fmaf(ca, DX, mcf));                    \
    const float svY = fmaf(cf2, wY, fmaf(ca, DY, mcf));                    \
    const float SX = p0X + r0, SY = p0Y + r1, ST = p0T + r2;               \
    const float rsX = frcp(SX), rsY = frcp(SY), rsT = frcp(ST);            \
    const float yX = (z0) - spX, yY = (z1) - spY, yT = (z2) - spT;         \
    const float ryX = rsX * yX, ryY = rsY * yY, ryT = rsT * yT;            \
    X   = fmaf(p0X, ryX, spX);  DX  = fmaf(p2X, ryX, svX);                 \
    Y   = fmaf(p0Y, ryY, spY);  DY  = fmaf(p2Y, ryY, svY);                 \
    TH  = fmaf(p0T, ryT, spT);  DTH = fmaf(p2T, ryT, DTH);                 \
    const float gX = r0 * rsX, gY = r1 * rsY, gT = r2 * rsT;               \
    const float kX = p2X * rsX, kY = p2Y * rsY, kT = p2T * rsT;            \
    px00 = p0X * gX; px02 = p2X * gX; px22 = fmaf(-kX, p2X, pvX);          \
    py11 = p0Y * gY; py13 = p2Y * gY; py33 = fmaf(-kY, p2Y, pvY);          \
    pt44 = p0T * gT; pt45 = p2T * gT; pt55 = fmaf(-kT, p2T, pvT);          \
    LT = fmaf(SX * SY, ST,                                                 \
              fmaf(yX, ryX, fmaf(yY, ryY, yT * ryT)));                     \
} while (0)

__global__ __launch_bounds__(64, 1) void ekf_kernel(
    const float* __restrict__ meas,        // (n_traj, T, 3)
    const float* __restrict__ init_state,  // (n_traj, 6)
    const float* __restrict__ dyna,        // (4,)
    const float* __restrict__ Qm,          // (6,6)
    const float* __restrict__ Rm,          // (3,3)
    const float* __restrict__ P0m,         // (6,6)
    float* __restrict__ out,               // (n_traj*T,)
    int n_traj, int T)
{
    int traj = blockIdx.x * 64 + threadIdx.x;
    if (traj >= n_traj) traj = n_traj - 1;   // dup lane rewrites same data

    // ---- wave-uniform constants (SGPRs) ----
    const float DTc  = 1.0f / 120.0f;
    const float fric = dyna[0], damp = dyna[1];
    const float ca   = 1.0f - DTc * damp;
    const float cf   = DTc * fric;
    const float mcf  = -cf;
    const float cf2  = 2.0f * cf;
    const float m4cb = -400.0f * cf;         // -4 * (100*cf)
    const float qx00 = Qm[0],  qxc = Qm[2],  qx22 = Qm[14];
    const float qy11 = Qm[7],  qyc = Qm[9],  qy33 = Qm[21];
    const float qt44 = Qm[28], qtc = Qm[29], qt55 = Qm[35];
    const float r0 = Rm[0], r1 = Rm[4], r2 = Rm[8];

    // ---- per-lane filter state ----
    float px00 = P0m[0],  px02 = P0m[2],  px22 = P0m[14];
    float py11 = P0m[7],  py13 = P0m[9],  py33 = P0m[21];
    float pt44 = P0m[28], pt45 = P0m[29], pt55 = P0m[35];

    const float2 s01 = *(const float2*)(init_state + 6 * traj);
    const float2 s23 = *(const float2*)(init_state + 6 * traj + 2);
    const float2 s45 = *(const float2*)(init_state + 6 * traj + 4);
    float X = s01.x, Y = s01.y, DX = s23.x, DY = s23.y, TH = s45.x, DTH = s45.y;

    // meas per-traj base: traj*3T floats = 6144 B (16B aligned); out: 2048 B
    const float4* __restrict__ zp4 = (const float4*)(meas + (size_t)traj * (size_t)(3 * T));
    float4*       __restrict__ op4 = (float4*)(out + (size_t)traj * (size_t)T);
    const int z4max = (3 * T) / 4 - 1;       // 383

    float4 A0, A1, A2, A3, A4, A5;           // current 8-step tile (24 floats)
    float4 B0, B1, B2, B3, B4, B5;           // next 8-step tile
    float4 L;                                // 4 losses

    // prologue: tile 0
    A0 = zp4[0]; A1 = zp4[1]; A2 = zp4[2];
    A3 = zp4[3]; A4 = zp4[4]; A5 = zp4[5];

    const int NI = T / 16;                   // 32 iterations, 16 steps each
    #pragma unroll 1
    for (int kk = 0; kk < NI; ++kk) {
        const int ib = kk * 12;              // float4 base of tile pair

        // prefetch tile B (steps 8..15) — never OOB (ib+11 <= 383)
        B0 = zp4[ib + 6];  B1 = zp4[ib + 7];  B2 = zp4[ib + 8];
        B3 = zp4[ib + 9];  B4 = zp4[ib + 10]; B5 = zp4[ib + 11];
        pin();   // loads issue here; stay in flight across A-steps

        // ---- 8 steps from A ----
        STEP(A0.x, A0.y, A0.z, L.x);
        STEP(A0.w, A1.x, A1.y, L.y);
        STEP(A1.z, A1.w, A2.x, L.z);
        STEP(A2.y, A2.z, A2.w, L.w);
        op4[kk * 4 + 0] = L;
        STEP(A3.x, A3.y, A3.z, L.x);
        STEP(A3.w, A4.x, A4.y, L.y);
        STEP(A4.z, A4.w, A5.x, L.z);
        STEP(A5.y, A5.z, A5.w, L.w);
        op4[kk * 4 + 1] = L;

        // prefetch next pair's tile A (clamped on final iteration; unused)
        const int ia = ib + 12;
        A0 = zp4[min(ia + 0, z4max)];
        A1 = zp4[min(ia + 1, z4max)];
        A2 = zp4[min(ia + 2, z4max)];
        A3 = zp4[min(ia + 3, z4max)];
        A4 = zp4[min(ia + 4, z4max)];
        A5 = zp4[min(ia + 5, z4max)];
        pin();   // loads issue here; stay in flight across B-steps

        // ---- 8 steps from B ----
        STEP(B0.x, B0.y, B0.z, L.x);
        STEP(B0.w, B1.x, B1.y, L.y);
        STEP(B1.z, B1.w, B2.x, L.z);
        STEP(B2.y, B2.z, B2.w, L.w);
        op4[kk * 4 + 2] = L;
        STEP(B3.x, B3.y, B3.z, L.x);
        STEP(B3.w, B4.x, B4.y, L.y);
        STEP(B4.z, B4.w, B5.x, L.z);
        STEP(B5.y, B5.z, B5.w, L.w);
        op4[kk * 4 + 3] = L;
    }
}

extern "C" void kernel_launch(void* const* d_in, const int* in_sizes, int n_in,
                              void* d_out, int out_size, void* d_ws, size_t ws_size,
                              hipStream_t stream) {
    const float* meas = (const float*)d_in[0];
    const float* init_state = (const float*)d_in[1];
    const float* dyna = (const float*)d_in[2];
    const float* Qm  = (const float*)d_in[3];
    const float* Rm  = (const float*)d_in[4];
    const float* P0m = (const float*)d_in[5];
    float* out = (float*)d_out;

    const int n_traj = in_sizes[1] / 6;
    const int T = in_sizes[0] / (n_traj * 3);

    const int grid = (n_traj + 63) / 64;
    ekf_kernel<<<grid, 64, 0, stream>>>(meas, init_state, dyna, Qm, Rm, P0m,
                                        out, n_traj, T);
}

// Round 12
// 151.797 us; speedup vs baseline: 1.0613x; 1.0613x over previous
//
#include <hip/hip_runtime.h>
#include <math.h>

// EKF over 2048 trajectories, T=512 serial steps. ONE LANE PER TRAJECTORY
// (32 waves); all three decomposed 2-state filters (x, y, theta) in-lane —
// three independent chains interleave to fill dependency-stall slots.
//
// R12 vs R11: R10/R11 spilled the 48-float z-tiles to scratch (VGPR=52/68
// vs ~90 live), and scratch reloads share vmcnt with the HBM prefetch ->
// every reload transitively waited on the prefetch. Fix is structural:
//   - 4-step ping-pong tiles (A/B = 24 floats) -> live set ~65 floats,
//     fits even a conservative allocation; no spill possible
//   - amdgpu_waves_per_eu(1,1): allocator budget = full register file
//   - no sched_barrier (let the scheduler hoist; m141 lesson)
//   - algebra: X_new = z - g*y, p00_new = r0 - r0*g, q+r premixed into S
//     (-3 insts/step, shorter chain).

#define CEXP 288.53900817779268f   // 200 * log2(e)

__device__ __forceinline__ float frcp(float x) { return __builtin_amdgcn_rcpf(x); }

// One EKF step for all three in-lane filters. z components are compile-time
// register selects; LT is an lvalue (float4 component) receiving the loss.
// tanh chain: w = 1/(exp2(c*v)+1); 1-tanh^2 = 4w(1-w); -cf*tanh = 2cf*w-cf.
// exp2 over/underflow round-trips correctly (inf->w=0, 0->w=1).
#define STEP(z0, z1, z2, LT) do {                                          \
    const float eX = exp2f(CEXP * DX);                                     \
    const float eY = exp2f(CEXP * DY);                                     \
    const float wX = frcp(eX + 1.0f);                                      \
    const float wY = frcp(eY + 1.0f);                                      \
    const float wwX = fmaf(wX, -wX, wX);                                   \
    const float wwY = fmaf(wY, -wY, wY);                                   \
    const float aX = fmaf(m4cb, wwX, ca);                                  \
    const float aY = fmaf(m4cb, wwY, ca);                                  \
    const float uX = fmaf(DTc, px22, px02);                                \
    const float uY = fmaf(DTc, py33, py13);                                \
    const float uT = fmaf(DTc, pt55, pt45);                                \
    const float SX = fmaf(DTc, px02 + uX, px00) + qx0r;                    \
    const float SY = fmaf(DTc, py13 + uY, py11) + qy1r;                    \
    const float ST = fmaf(DTc, pt45 + uT, pt44) + qt4r;                    \
    const float p2X = fmaf(aX, uX, qxc);                                   \
    const float p2Y = fmaf(aY, uY, qyc);                                   \
    const float p2T = uT + qtc;                                            \
    const float pvX = fmaf(aX * px22, aX, qx22);                           \
    const float pvY = fmaf(aY * py33, aY, qy33);                           \
    const float pvT = pt55 + qt55;                                         \
    const float spX = fmaf(DTc, DX, X);                                    \
    const float spY = fmaf(DTc, DY, Y);                                    \
    const float spT = fmaf(DTc, DTH, TH);                                  \
    const float svX = fmaf(cf2, wX, fmaf(ca, DX, mcf));                    \
    const float svY = fmaf(cf2, wY, fmaf(ca, DY, mcf));                    \
    const float rsX = frcp(SX), rsY = frcp(SY), rsT = frcp(ST);            \
    const float yX = (z0) - spX, yY = (z1) - spY, yT = (z2) - spT;         \
    const float ryX = rsX * yX, ryY = rsY * yY, ryT = rsT * yT;            \
    const float gX = r0 * rsX, gY = r1 * rsY, gT = r2 * rsT;               \
    const float kX = p2X * rsX, kY = p2Y * rsY, kT = p2T * rsT;            \
    X   = fmaf(-gX, yX, (z0));                                             \
    Y   = fmaf(-gY, yY, (z1));                                             \
    TH  = fmaf(-gT, yT, (z2));                                             \
    DX  = fmaf(p2X, ryX, svX);                                             \
    DY  = fmaf(p2Y, ryY, svY);                                             \
    DTH = fmaf(p2T, ryT, DTH);                                             \
    px00 = fmaf(-r0, gX, r0);                                              \
    py11 = fmaf(-r1, gY, r1);                                              \
    pt44 = fmaf(-r2, gT, r2);                                              \
    px02 = p2X * gX; py13 = p2Y * gY; pt45 = p2T * gT;                     \
    px22 = fmaf(-kX, p2X, pvX);                                            \
    py33 = fmaf(-kY, p2Y, pvY);                                            \
    pt55 = fmaf(-kT, p2T, pvT);                                            \
    LT = fmaf(SX * SY, ST, fmaf(yX, ryX, fmaf(yY, ryY, yT * ryT)));        \
} while (0)

__global__ __launch_bounds__(64)
__attribute__((amdgpu_waves_per_eu(1, 1)))
void ekf_kernel(
    const float* __restrict__ meas,        // (n_traj, T, 3)
    const float* __restrict__ init_state,  // (n_traj, 6)
    const float* __restrict__ dyna,        // (4,)
    const float* __restrict__ Qm,          // (6,6)
    const float* __restrict__ Rm,          // (3,3)
    const float* __restrict__ P0m,         // (6,6)
    float* __restrict__ out,               // (n_traj*T,)
    int n_traj, int T)
{
    int traj = blockIdx.x * 64 + threadIdx.x;
    if (traj >= n_traj) traj = n_traj - 1;   // dup lane rewrites same data

    // ---- wave-uniform constants (SGPRs) ----
    const float DTc  = 1.0f / 120.0f;
    const float fric = dyna[0], damp = dyna[1];
    const float ca   = 1.0f - DTc * damp;
    const float cf   = DTc * fric;
    const float mcf  = -cf;
    const float cf2  = 2.0f * cf;
    const float m4cb = -400.0f * cf;         // -4 * (100*cf)
    const float r0 = Rm[0], r1 = Rm[4], r2 = Rm[8];
    const float qx0r = Qm[0]  + r0;          // q00 + r0 premixed into S
    const float qy1r = Qm[7]  + r1;
    const float qt4r = Qm[28] + r2;
    const float qxc = Qm[2],  qx22 = Qm[14];
    const float qyc = Qm[9],  qy33 = Qm[21];
    const float qtc = Qm[29], qt55 = Qm[35];

    // ---- per-lane filter state ----
    float px00 = P0m[0],  px02 = P0m[2],  px22 = P0m[14];
    float py11 = P0m[7],  py13 = P0m[9],  py33 = P0m[21];
    float pt44 = P0m[28], pt45 = P0m[29], pt55 = P0m[35];

    const float2 s01 = *(const float2*)(init_state + 6 * traj);
    const float2 s23 = *(const float2*)(init_state + 6 * traj + 2);
    const float2 s45 = *(const float2*)(init_state + 6 * traj + 4);
    float X = s01.x, Y = s01.y, DX = s23.x, DY = s23.y, TH = s45.x, DTH = s45.y;

    // meas per-traj base: traj*3T floats = 6144 B (16B aligned); out: 2048 B
    const float4* __restrict__ zp4 = (const float4*)(meas + (size_t)traj * (size_t)(3 * T));
    float4*       __restrict__ op4 = (float4*)(out + (size_t)traj * (size_t)T);
    const int z4max = (3 * T) / 4 - 1;       // 383

    float4 A0, A1, A2;                       // current 4-step tile (12 z)
    float4 B0, B1, B2;                       // next 4-step tile
    float4 L;                                // 4 losses

    // prologue: tile 0
    A0 = zp4[0]; A1 = zp4[1]; A2 = zp4[2];

    const int NI = T / 8;                    // 64 iterations, 8 steps each
    #pragma unroll 1
    for (int kk = 0; kk < NI; ++kk) {
        const int ib = kk * 6;               // float4 base of tile pair

        // prefetch tile B (steps 4..7) — never OOB (ib+5 <= 383)
        B0 = zp4[ib + 3]; B1 = zp4[ib + 4]; B2 = zp4[ib + 5];

        // ---- 4 steps from A ----
        STEP(A0.x, A0.y, A0.z, L.x);
        STEP(A0.w, A1.x, A1.y, L.y);
        STEP(A1.z, A1.w, A2.x, L.z);
        STEP(A2.y, A2.z, A2.w, L.w);
        op4[kk * 2 + 0] = L;

        // prefetch next pair's tile A (clamped on final iteration; unused)
        const int ia = ib + 6;
        A0 = zp4[min(ia + 0, z4max)];
        A1 = zp4[min(ia + 1, z4max)];
        A2 = zp4[min(ia + 2, z4max)];

        // ---- 4 steps from B ----
        STEP(B0.x, B0.y, B0.z, L.x);
        STEP(B0.w, B1.x, B1.y, L.y);
        STEP(B1.z, B1.w, B2.x, L.z);
        STEP(B2.y, B2.z, B2.w, L.w);
        op4[kk * 2 + 1] = L;
    }
}

extern "C" void kernel_launch(void* const* d_in, const int* in_sizes, int n_in,
                              void* d_out, int out_size, void* d_ws, size_t ws_size,
                              hipStream_t stream) {
    const float* meas = (const float*)d_in[0];
    const float* init_state = (const float*)d_in[1];
    const float* dyna = (const float*)d_in[2];
    const float* Qm  = (const float*)d_in[3];
    const float* Rm  = (const float*)d_in[4];
    const float* P0m = (const float*)d_in[5];
    float* out = (float*)d_out;

    const int n_traj = in_sizes[1] / 6;
    const int T = in_sizes[0] / (n_traj * 3);

    const int grid = (n_traj + 63) / 64;
    ekf_kernel<<<grid, 64, 0, stream>>>(meas, init_state, dyna, Qm, Rm, P0m,
                                        out, n_traj, T);
}